// Round 1
// baseline (1673.942 us; speedup 1.0000x reference)
//
#include <hip/hip_runtime.h>
#include <math.h>

#define F_IN 128
#define HID  64
#define NCLS 40

// ---------------- degree / norm ----------------

__global__ void count_deg(const int* __restrict__ dst, int E, float* __restrict__ deg) {
    int e = blockIdx.x * blockDim.x + threadIdx.x;
    if (e < E) atomicAdd(&deg[dst[e]], 1.0f);
}

__global__ void finalize_dinv(float* __restrict__ deg, int n) {
    int i = blockIdx.x * blockDim.x + threadIdx.x;
    if (i < n) deg[i] = rsqrtf(deg[i] + 1.0f);   // +1 for the self loop; deg>0 always
}

// ---------------- layer 1 GEMM: h1 = x @ W1  ----------------
// 4 nodes per 256-thread block; W1 (128x64 = 32KB) staged in LDS.
__global__ __launch_bounds__(256) void gemm1(const float* __restrict__ x,
                                             const float* __restrict__ W1,
                                             float* __restrict__ h1, int n) {
    __shared__ float Ws[F_IN * HID];   // 32 KB
    __shared__ float xs[4][F_IN];      // 2 KB
    int tid = threadIdx.x;
    for (int i = tid; i < F_IN * HID; i += 256) Ws[i] = W1[i];
    int node0 = blockIdx.x * 4;
    for (int i = tid; i < 4 * F_IN; i += 256) {
        int nl = i >> 7, k = i & (F_IN - 1);
        int node = node0 + nl;
        xs[nl][k] = (node < n) ? x[node * F_IN + k] : 0.0f;
    }
    __syncthreads();
    int nl = tid >> 6;        // wave id: all 64 lanes share a node -> xs broadcast
    int o  = tid & 63;        // Ws[k*64+o]: banks o%32, 2 lanes/bank = conflict-free
    int node = node0 + nl;
    if (node >= n) return;
    float acc = 0.0f;
#pragma unroll 8
    for (int k = 0; k < F_IN; ++k) acc += xs[nl][k] * Ws[k * HID + o];
    h1[node * HID + o] = acc;
}

// ---------------- aggregation 1 ----------------
// self-loop term initializes out1 (also overwrites 0xAA poison)
__global__ void selfloop1(const float* __restrict__ h1, const float* __restrict__ dinv,
                          float* __restrict__ out1, int n) {
    int gid = blockIdx.x * blockDim.x + threadIdx.x;
    if (gid < n * HID) {
        float di = dinv[gid >> 6];
        out1[gid] = h1[gid] * di * di;
    }
}

// one edge per 64-lane group; lane = feature -> 64 consecutive atomics (256B segment)
__global__ __launch_bounds__(256) void agg1(const int* __restrict__ src, const int* __restrict__ dst,
                                            const float* __restrict__ dinv,
                                            const float* __restrict__ h1,
                                            float* __restrict__ out1, int E) {
    int lane = threadIdx.x & 63;
    int e = blockIdx.x * 4 + (threadIdx.x >> 6);
    if (e >= E) return;
    int s = src[e], d = dst[e];
    float w = dinv[s] * dinv[d];
    atomicAdd(&out1[d * HID + lane], h1[s * HID + lane] * w);
}

// ---------------- layer 2 GEMM: h2 = relu(out1 + b1) @ W2 ----------------
__global__ __launch_bounds__(256) void gemm2(const float* __restrict__ a,
                                             const float* __restrict__ W2,
                                             const float* __restrict__ b1,
                                             float* __restrict__ h2, int n) {
    __shared__ float Ws[HID * NCLS];   // 10 KB
    __shared__ float xs[4][HID];       // 1 KB
    int tid = threadIdx.x;
    for (int i = tid; i < HID * NCLS; i += 256) Ws[i] = W2[i];
    int node0 = blockIdx.x * 4;
    for (int i = tid; i < 4 * HID; i += 256) {
        int nl = i >> 6, k = i & 63;
        int node = node0 + nl;
        xs[nl][k] = (node < n) ? fmaxf(a[node * HID + k] + b1[k], 0.0f) : 0.0f;
    }
    __syncthreads();
    if (tid < 4 * NCLS) {
        int nl = tid / NCLS, c = tid % NCLS;
        int node = node0 + nl;
        if (node < n) {
            float acc = 0.0f;
#pragma unroll 8
            for (int k = 0; k < HID; ++k) acc += xs[nl][k] * Ws[k * NCLS + c];
            h2[node * NCLS + c] = acc;
        }
    }
}

// ---------------- aggregation 2 (into d_out) ----------------
__global__ void selfloop2(const float* __restrict__ h2, const float* __restrict__ dinv,
                          float* __restrict__ out, int n) {
    int gid = blockIdx.x * blockDim.x + threadIdx.x;
    if (gid < n * NCLS) {
        float di = dinv[gid / NCLS];
        out[gid] = h2[gid] * di * di;
    }
}

// thread per (edge, class)
__global__ __launch_bounds__(256) void agg2(const int* __restrict__ src, const int* __restrict__ dst,
                                            const float* __restrict__ dinv,
                                            const float* __restrict__ h2,
                                            float* __restrict__ out, int E) {
    int gid = blockIdx.x * 256 + threadIdx.x;     // max 128M < 2^31
    if (gid >= E * NCLS) return;
    int e = gid / NCLS;
    int c = gid - e * NCLS;
    int s = src[e], d = dst[e];
    float w = dinv[s] * dinv[d];
    atomicAdd(&out[d * NCLS + c], h2[s * NCLS + c] * w);
}

// ---------------- +b2 then log_softmax, in place on d_out ----------------
__global__ __launch_bounds__(256) void logsm(float* __restrict__ out, const float* __restrict__ b2,
                                             int n) {
    int lane = threadIdx.x & 63;
    int i = blockIdx.x * 4 + (threadIdx.x >> 6);
    if (i >= n) return;
    float v = (lane < NCLS) ? out[i * NCLS + lane] + b2[lane] : -INFINITY;
    float m = v;
    for (int off = 32; off; off >>= 1) m = fmaxf(m, __shfl_xor(m, off, 64));
    float ex = (lane < NCLS) ? expf(v - m) : 0.0f;
    float s = ex;
    for (int off = 32; off; off >>= 1) s += __shfl_xor(s, off, 64);
    if (lane < NCLS) out[i * NCLS + lane] = v - m - logf(s);
}

extern "C" void kernel_launch(void* const* d_in, const int* in_sizes, int n_in,
                              void* d_out, int out_size, void* d_ws, size_t ws_size,
                              hipStream_t stream) {
    const float* x  = (const float*)d_in[0];
    const int*   ei = (const int*)d_in[1];     // int64 in ref -> harness delivers int32
    const float* W1 = (const float*)d_in[2];
    const float* b1 = (const float*)d_in[3];
    const float* W2 = (const float*)d_in[4];
    const float* b2 = (const float*)d_in[5];
    float* out = (float*)d_out;

    int n = in_sizes[0] / F_IN;        // 100000
    int E = in_sizes[1] / 2;           // 3200000
    const int* src = ei;
    const int* dst = ei + E;

    char* ws = (char*)d_ws;
    float* dinv = (float*)ws;                                        // n floats
    float* bufA = (float*)(ws + (size_t)512 * 1024);                 // h1 (25.6MB) then h2 (16MB)
    float* bufB = (float*)(ws + (size_t)512 * 1024 + (size_t)26 * 1024 * 1024);  // out1 (25.6MB)

    hipMemsetAsync(dinv, 0, (size_t)n * sizeof(float), stream);
    count_deg<<<(E + 255) / 256, 256, 0, stream>>>(dst, E, dinv);
    finalize_dinv<<<(n + 255) / 256, 256, 0, stream>>>(dinv, n);

    gemm1<<<(n + 3) / 4, 256, 0, stream>>>(x, W1, bufA, n);
    selfloop1<<<(n * HID + 255) / 256, 256, 0, stream>>>(bufA, dinv, bufB, n);
    agg1<<<(E + 3) / 4, 256, 0, stream>>>(src, dst, dinv, bufA, bufB, E);

    gemm2<<<(n + 3) / 4, 256, 0, stream>>>(bufB, W2, b1, bufA, n);
    selfloop2<<<(n * NCLS + 255) / 256, 256, 0, stream>>>(bufA, dinv, out, n);
    agg2<<<(int)(((long long)E * NCLS + 255) / 256), 256, 0, stream>>>(src, dst, dinv, bufA, out, E);

    logsm<<<(n + 3) / 4, 256, 0, stream>>>(out, b2, n);
}

// Round 2
// 1210.606 us; speedup vs baseline: 1.3827x; 1.3827x over previous
//
#include <hip/hip_runtime.h>
#include <math.h>

#define F_IN 128
#define HID  64
#define NCLS 40

// ---------------- degree histogram (int) ----------------
__global__ void histo(const int* __restrict__ dst, int E, int* __restrict__ cnt) {
    int e = blockIdx.x * blockDim.x + threadIdx.x;
    if (e < E) atomicAdd(&cnt[dst[e]], 1);
}

__global__ void finalize_dinv(const int* __restrict__ cnt, float* __restrict__ dinv, int n) {
    int i = blockIdx.x * blockDim.x + threadIdx.x;
    if (i < n) dinv[i] = rsqrtf((float)cnt[i] + 1.0f);   // +1 self loop
}

// ---------------- exclusive scan of cnt -> ptr (3 kernels) ----------------
__global__ __launch_bounds__(256) void scanA(const int* __restrict__ cnt, int* __restrict__ ptr,
                                             int* __restrict__ bsum, int n) {
    __shared__ int s[256];
    int tid = threadIdx.x;
    int i = blockIdx.x * 256 + tid;
    int v = (i < n) ? cnt[i] : 0;
    s[tid] = v; __syncthreads();
    for (int off = 1; off < 256; off <<= 1) {
        int t = (tid >= off) ? s[tid - off] : 0;
        __syncthreads();
        s[tid] += t;
        __syncthreads();
    }
    if (i < n) ptr[i] = s[tid] - v;       // exclusive within block
    if (tid == 255) bsum[blockIdx.x] = s[255];
}

__global__ __launch_bounds__(512) void scanB(int* __restrict__ bsum, int nb) {
    __shared__ int s[512];
    int tid = threadIdx.x;
    int v = (tid < nb) ? bsum[tid] : 0;
    s[tid] = v; __syncthreads();
    for (int off = 1; off < 512; off <<= 1) {
        int t = (tid >= off) ? s[tid - off] : 0;
        __syncthreads();
        s[tid] += t;
        __syncthreads();
    }
    if (tid < nb) bsum[tid] = s[tid] - v; // exclusive block offsets
}

__global__ __launch_bounds__(256) void scanC(int* __restrict__ ptr, const int* __restrict__ bsum,
                                             int* __restrict__ cursor, int n, int E) {
    int i = blockIdx.x * 256 + threadIdx.x;
    if (i < n) {
        int p = ptr[i] + bsum[blockIdx.x];
        ptr[i] = p;
        cursor[i] = p;
    }
    if (i == 0) ptr[n] = E;
}

// ---------------- scatter-sort edges by dst ----------------
__global__ void scatter_sort(const int* __restrict__ src, const int* __restrict__ dst,
                             const float* __restrict__ dinv, int* __restrict__ cursor,
                             int* __restrict__ sIdx, float* __restrict__ sW, int E) {
    int e = blockIdx.x * blockDim.x + threadIdx.x;
    if (e >= E) return;
    int s_ = src[e], d = dst[e];
    int pos = atomicAdd(&cursor[d], 1);
    sIdx[pos] = s_;
    sW[pos]   = dinv[s_];                 // dinv[dst] applied once per node in gather
}

// ---------------- layer 1 GEMM: h1 = x @ W1 ----------------
__global__ __launch_bounds__(256) void gemm1(const float* __restrict__ x,
                                             const float* __restrict__ W1,
                                             float* __restrict__ h1, int n) {
    __shared__ float Ws[F_IN * HID];   // 32 KB
    __shared__ float xs[4][F_IN];      // 2 KB
    int tid = threadIdx.x;
    for (int i = tid; i < F_IN * HID; i += 256) Ws[i] = W1[i];
    int node0 = blockIdx.x * 4;
    for (int i = tid; i < 4 * F_IN; i += 256) {
        int nl = i >> 7, k = i & (F_IN - 1);
        int node = node0 + nl;
        xs[nl][k] = (node < n) ? x[(size_t)node * F_IN + k] : 0.0f;
    }
    __syncthreads();
    int nl = tid >> 6;
    int o  = tid & 63;
    int node = node0 + nl;
    if (node >= n) return;
    float acc = 0.0f;
#pragma unroll 8
    for (int k = 0; k < F_IN; ++k) acc = fmaf(xs[nl][k], Ws[k * HID + o], acc);
    h1[(size_t)node * HID + o] = acc;
}

// ---------------- CSR gather aggregation: hout[i] = sum_j w_ij * hin[src_j]  ----------------
// one wave per node, lane = feature; optional relu(.+bias) epilogue
template<bool RELU>
__global__ __launch_bounds__(256) void gather(const int* __restrict__ ptr,
                                              const int* __restrict__ sIdx,
                                              const float* __restrict__ sW,
                                              const float* __restrict__ dinv,
                                              const float* __restrict__ hin,
                                              const float* __restrict__ bias,
                                              float* __restrict__ hout, int n) {
    int lane = threadIdx.x & 63;
    int node = blockIdx.x * 4 + (threadIdx.x >> 6);
    if (node >= n) return;
    int beg = ptr[node], end = ptr[node + 1];
    float di = dinv[node];
    float acc = hin[(size_t)node * HID + lane] * di * di;   // self loop
    for (int j = beg; j < end; ++j) {
        int   s = sIdx[j];                 // wave-uniform broadcast load
        float w = sW[j] * di;
        acc = fmaf(hin[(size_t)s * HID + lane], w, acc);
    }
    if (RELU) acc = fmaxf(acc + bias[lane], 0.0f);
    hout[(size_t)node * HID + lane] = acc;
}

// ---------------- out = log_softmax(g @ W2 + b2), wave per node ----------------
__global__ __launch_bounds__(256) void gemm2_logsm(const float* __restrict__ g,
                                                   const float* __restrict__ W2,
                                                   const float* __restrict__ b2,
                                                   float* __restrict__ out, int n) {
    __shared__ float Ws[HID * NCLS];   // 10 KB
    __shared__ float xs[4][HID];
    int tid = threadIdx.x;
    for (int i = tid; i < HID * NCLS; i += 256) Ws[i] = W2[i];
    int node0 = blockIdx.x * 4;
    for (int i = tid; i < 4 * HID; i += 256) {
        int nl = i >> 6, k = i & 63;
        int node = node0 + nl;
        xs[nl][k] = (node < n) ? g[(size_t)node * HID + k] : 0.0f;
    }
    __syncthreads();
    int lane = tid & 63, nl = tid >> 6;
    int node = node0 + nl;
    if (node >= n) return;                 // wave-uniform (grid padding only)
    float acc;
    if (lane < NCLS) {
        acc = b2[lane];
#pragma unroll
        for (int k = 0; k < HID; ++k) acc = fmaf(xs[nl][k], Ws[k * NCLS + lane], acc);
    } else {
        acc = -INFINITY;
    }
    float m = acc;
    for (int off = 32; off; off >>= 1) m = fmaxf(m, __shfl_xor(m, off, 64));
    float ex = (lane < NCLS) ? expf(acc - m) : 0.0f;
    float s = ex;
    for (int off = 32; off; off >>= 1) s += __shfl_xor(s, off, 64);
    if (lane < NCLS) out[(size_t)node * NCLS + lane] = acc - m - logf(s);
}

extern "C" void kernel_launch(void* const* d_in, const int* in_sizes, int n_in,
                              void* d_out, int out_size, void* d_ws, size_t ws_size,
                              hipStream_t stream) {
    const float* x  = (const float*)d_in[0];
    const int*   ei = (const int*)d_in[1];
    const float* W1 = (const float*)d_in[2];
    const float* b1 = (const float*)d_in[3];
    const float* W2 = (const float*)d_in[4];
    const float* b2 = (const float*)d_in[5];
    float* out = (float*)d_out;

    int n = in_sizes[0] / F_IN;        // 100000
    int E = in_sizes[1] / 2;           // 3200000
    const int* src = ei;
    const int* dst = ei + E;

    // workspace layout
    char* ws = (char*)d_ws;
    const size_t MB = 1024 * 1024;
    int*   cnt     = (int*)  (ws);                 // n ints        (0.5 MB slot)
    int*   ptr     = (int*)  (ws + 1 * 512 * 1024);// n+1 ints
    int*   cursor  = (int*)  (ws + 2 * 512 * 1024);// n ints
    float* dinv    = (float*)(ws + 3 * 512 * 1024);// n floats
    int*   bsum    = (int*)  (ws + 4 * 512 * 1024);// <=1024 ints
    int*   sIdx    = (int*)  (ws + 5 * 512 * 1024);             // E ints   (13 MB slot)
    float* sW      = (float*)(ws + 5 * 512 * 1024 + 13 * MB);   // E floats (13 MB slot)
    float* bufA    = (float*)(ws + 5 * 512 * 1024 + 26 * MB);   // n*64 f   (26 MB slot): h1, later g
    float* bufB    = (float*)(ws + 5 * 512 * 1024 + 52 * MB);   // n*64 f   (26 MB slot): h (relu out)

    int nbA = (n + 255) / 256;         // 391 scan blocks (<=512)

    hipMemsetAsync(cnt, 0, (size_t)n * sizeof(int), stream);
    histo<<<(E + 255) / 256, 256, 0, stream>>>(dst, E, cnt);
    finalize_dinv<<<nbA, 256, 0, stream>>>(cnt, dinv, n);
    scanA<<<nbA, 256, 0, stream>>>(cnt, ptr, bsum, n);
    scanB<<<1, 512, 0, stream>>>(bsum, nbA);
    scanC<<<nbA, 256, 0, stream>>>(ptr, bsum, cursor, n, E);
    scatter_sort<<<(E + 255) / 256, 256, 0, stream>>>(src, dst, dinv, cursor, sIdx, sW, E);

    gemm1<<<(n + 3) / 4, 256, 0, stream>>>(x, W1, bufA, n);
    gather<true ><<<(n + 3) / 4, 256, 0, stream>>>(ptr, sIdx, sW, dinv, bufA, b1, bufB, n); // h = relu(Âh1+b1)
    gather<false><<<(n + 3) / 4, 256, 0, stream>>>(ptr, sIdx, sW, dinv, bufB, b1, bufA, n); // g = Âh
    gemm2_logsm<<<(n + 3) / 4, 256, 0, stream>>>(bufA, W2, b2, out, n);
}

// Round 3
// 919.797 us; speedup vs baseline: 1.8199x; 1.3162x over previous
//
#include <hip/hip_runtime.h>
#include <math.h>

#define F_IN 128
#define HID  64
#define NCLS 40

// ---------------- degree histogram (int) ----------------
__global__ void histo(const int* __restrict__ dst, int E, int* __restrict__ cnt) {
    int e = blockIdx.x * blockDim.x + threadIdx.x;
    if (e < E) atomicAdd(&cnt[dst[e]], 1);
}

__global__ void finalize_dinv(const int* __restrict__ cnt, float* __restrict__ dinv, int n) {
    int i = blockIdx.x * blockDim.x + threadIdx.x;
    if (i < n) dinv[i] = rsqrtf((float)cnt[i] + 1.0f);   // +1 self loop
}

// ---------------- exclusive scan of cnt -> ptr ----------------
__global__ __launch_bounds__(256) void scanA(const int* __restrict__ cnt, int* __restrict__ ptr,
                                             int* __restrict__ bsum, int n) {
    __shared__ int s[256];
    int tid = threadIdx.x;
    int i = blockIdx.x * 256 + tid;
    int v = (i < n) ? cnt[i] : 0;
    s[tid] = v; __syncthreads();
    for (int off = 1; off < 256; off <<= 1) {
        int t = (tid >= off) ? s[tid - off] : 0;
        __syncthreads();
        s[tid] += t;
        __syncthreads();
    }
    if (i < n) ptr[i] = s[tid] - v;
    if (tid == 255) bsum[blockIdx.x] = s[255];
}

__global__ __launch_bounds__(512) void scanB(int* __restrict__ bsum, int nb) {
    __shared__ int s[512];
    int tid = threadIdx.x;
    int v = (tid < nb) ? bsum[tid] : 0;
    s[tid] = v; __syncthreads();
    for (int off = 1; off < 512; off <<= 1) {
        int t = (tid >= off) ? s[tid - off] : 0;
        __syncthreads();
        s[tid] += t;
        __syncthreads();
    }
    if (tid < nb) bsum[tid] = s[tid] - v;
}

__global__ __launch_bounds__(256) void scanC(int* __restrict__ ptr, const int* __restrict__ bsum,
                                             int* __restrict__ cursor, int n, int E) {
    int i = blockIdx.x * 256 + threadIdx.x;
    if (i < n) {
        int p = ptr[i] + bsum[blockIdx.x];
        ptr[i] = p;
        cursor[i] = p;
    }
    if (i == 0) ptr[n] = E;
}

// ---------------- scatter-sort edges by dst (sIdx only; weights recomputed in gather) ----------------
__global__ void scatter_sort(const int* __restrict__ src, const int* __restrict__ dst,
                             int* __restrict__ cursor, int* __restrict__ sIdx, int E) {
    int e = blockIdx.x * blockDim.x + threadIdx.x;
    if (e >= E) return;
    int s_ = src[e], d = dst[e];
    int pos = atomicAdd(&cursor[d], 1);
    sIdx[pos] = s_;
}

// ---------------- layer 1 GEMM: h1 = x @ W1 ----------------
__global__ __launch_bounds__(256) void gemm1(const float* __restrict__ x,
                                             const float* __restrict__ W1,
                                             float* __restrict__ h1, int n) {
    __shared__ float Ws[F_IN * HID];   // 32 KB
    __shared__ float xs[4][F_IN];      // 2 KB
    int tid = threadIdx.x;
    for (int i = tid; i < F_IN * HID; i += 256) Ws[i] = W1[i];
    int node0 = blockIdx.x * 4;
    for (int i = tid; i < 4 * F_IN; i += 256) {
        int nl = i >> 7, k = i & (F_IN - 1);
        int node = node0 + nl;
        xs[nl][k] = (node < n) ? x[(size_t)node * F_IN + k] : 0.0f;
    }
    __syncthreads();
    int nl = tid >> 6;
    int o  = tid & 63;
    int node = node0 + nl;
    if (node >= n) return;
    float acc = 0.0f;
#pragma unroll 8
    for (int k = 0; k < F_IN; ++k) acc = fmaf(xs[nl][k], Ws[k * HID + o], acc);
    h1[(size_t)node * HID + o] = acc;
}

// ---------------- CSR gather: wave per node, 4 rows per load instruction, x2 unroll ----------------
// lane = (grp = edge slot 0..3, fq = float4 chunk 0..15). One global_load_dwordx4
// fetches 4 edges' 256B rows (1KB); two in flight -> 8 edges/iter per wave.
template<bool RELU>
__global__ __launch_bounds__(256) void gather8(const int* __restrict__ ptr,
                                               const int* __restrict__ sIdx,
                                               const float* __restrict__ dinv,
                                               const float* __restrict__ hin,
                                               const float* __restrict__ bias,
                                               float* __restrict__ hout, int n) {
    int tid  = threadIdx.x;
    int lane = tid & 63;
    int node = blockIdx.x * 4 + (tid >> 6);
    if (node >= n) return;
    int grp = lane >> 4;          // edge slot within iteration
    int fq  = lane & 15;          // float4 index within 64-float row
    int beg = ptr[node], end = ptr[node + 1];
    float di = dinv[node];

    float4 a0 = make_float4(0.f, 0.f, 0.f, 0.f);
    float4 a1 = make_float4(0.f, 0.f, 0.f, 0.f);

    if (grp == 0) {  // self loop
        float4 v = ((const float4*)(hin + (size_t)node * HID))[fq];
        float w = di * di;
        a0.x = v.x * w; a0.y = v.y * w; a0.z = v.z * w; a0.w = v.w * w;
    }

    for (int j0 = beg; j0 < end; j0 += 8) {
        int ja = j0 + grp;
        int jb = j0 + 4 + grp;
        bool va = ja < end, vb = jb < end;
        int sa = sIdx[va ? ja : beg];
        int sb = sIdx[vb ? jb : beg];
        float wa = va ? dinv[sa] * di : 0.f;
        float wb = vb ? dinv[sb] * di : 0.f;
        float4 ra = ((const float4*)(hin + (size_t)sa * HID))[fq];
        float4 rb = ((const float4*)(hin + (size_t)sb * HID))[fq];
        a0.x = fmaf(ra.x, wa, a0.x); a0.y = fmaf(ra.y, wa, a0.y);
        a0.z = fmaf(ra.z, wa, a0.z); a0.w = fmaf(ra.w, wa, a0.w);
        a1.x = fmaf(rb.x, wb, a1.x); a1.y = fmaf(rb.y, wb, a1.y);
        a1.z = fmaf(rb.z, wb, a1.z); a1.w = fmaf(rb.w, wb, a1.w);
    }
    a0.x += a1.x; a0.y += a1.y; a0.z += a1.z; a0.w += a1.w;
#pragma unroll
    for (int off = 16; off < 64; off <<= 1) {
        a0.x += __shfl_xor(a0.x, off, 64);
        a0.y += __shfl_xor(a0.y, off, 64);
        a0.z += __shfl_xor(a0.z, off, 64);
        a0.w += __shfl_xor(a0.w, off, 64);
    }
    if (grp == 0) {
        if (RELU) {
            float4 b = ((const float4*)bias)[fq];
            a0.x = fmaxf(a0.x + b.x, 0.f);
            a0.y = fmaxf(a0.y + b.y, 0.f);
            a0.z = fmaxf(a0.z + b.z, 0.f);
            a0.w = fmaxf(a0.w + b.w, 0.f);
        }
        ((float4*)(hout + (size_t)node * HID))[fq] = a0;
    }
}

// ---------------- out = log_softmax(g @ W2 + b2), wave per node ----------------
__global__ __launch_bounds__(256) void gemm2_logsm(const float* __restrict__ g,
                                                   const float* __restrict__ W2,
                                                   const float* __restrict__ b2,
                                                   float* __restrict__ out, int n) {
    __shared__ float Ws[HID * NCLS];   // 10 KB
    __shared__ float xs[4][HID];
    int tid = threadIdx.x;
    for (int i = tid; i < HID * NCLS; i += 256) Ws[i] = W2[i];
    int node0 = blockIdx.x * 4;
    for (int i = tid; i < 4 * HID; i += 256) {
        int nl = i >> 6, k = i & 63;
        int node = node0 + nl;
        xs[nl][k] = (node < n) ? g[(size_t)node * HID + k] : 0.0f;
    }
    __syncthreads();
    int lane = tid & 63, nl = tid >> 6;
    int node = node0 + nl;
    if (node >= n) return;
    float acc;
    if (lane < NCLS) {
        acc = b2[lane];
#pragma unroll
        for (int k = 0; k < HID; ++k) acc = fmaf(xs[nl][k], Ws[k * NCLS + lane], acc);
    } else {
        acc = -INFINITY;
    }
    float m = acc;
    for (int off = 32; off; off >>= 1) m = fmaxf(m, __shfl_xor(m, off, 64));
    float ex = (lane < NCLS) ? expf(acc - m) : 0.0f;
    float s = ex;
    for (int off = 32; off; off >>= 1) s += __shfl_xor(s, off, 64);
    if (lane < NCLS) out[(size_t)node * NCLS + lane] = acc - m - logf(s);
}

extern "C" void kernel_launch(void* const* d_in, const int* in_sizes, int n_in,
                              void* d_out, int out_size, void* d_ws, size_t ws_size,
                              hipStream_t stream) {
    const float* x  = (const float*)d_in[0];
    const int*   ei = (const int*)d_in[1];
    const float* W1 = (const float*)d_in[2];
    const float* b1 = (const float*)d_in[3];
    const float* W2 = (const float*)d_in[4];
    const float* b2 = (const float*)d_in[5];
    float* out = (float*)d_out;

    int n = in_sizes[0] / F_IN;        // 100000
    int E = in_sizes[1] / 2;           // 3200000
    const int* src = ei;
    const int* dst = ei + E;

    // workspace layout
    char* ws = (char*)d_ws;
    const size_t MB = 1024 * 1024;
    int*   cnt     = (int*)  (ws);                     // n ints
    int*   ptr     = (int*)  (ws + 1 * 512 * 1024);    // n+1 ints
    int*   cursor  = (int*)  (ws + 2 * 512 * 1024);    // n ints
    float* dinv    = (float*)(ws + 3 * 512 * 1024);    // n floats
    int*   bsum    = (int*)  (ws + 4 * 512 * 1024);    // <=512 ints
    int*   sIdx    = (int*)  (ws + 5 * 512 * 1024);            // E ints (13 MB slot)
    float* bufA    = (float*)(ws + 5 * 512 * 1024 + 13 * MB);  // n*64 f (26 MB slot): h1, later g
    float* bufB    = (float*)(ws + 5 * 512 * 1024 + 39 * MB);  // n*64 f (26 MB slot): h (relu out)

    int nbA = (n + 255) / 256;         // 391 scan blocks (<=512)

    hipMemsetAsync(cnt, 0, (size_t)n * sizeof(int), stream);
    histo<<<(E + 255) / 256, 256, 0, stream>>>(dst, E, cnt);
    finalize_dinv<<<nbA, 256, 0, stream>>>(cnt, dinv, n);
    scanA<<<nbA, 256, 0, stream>>>(cnt, ptr, bsum, n);
    scanB<<<1, 512, 0, stream>>>(bsum, nbA);
    scanC<<<nbA, 256, 0, stream>>>(ptr, bsum, cursor, n, E);
    scatter_sort<<<(E + 255) / 256, 256, 0, stream>>>(src, dst, cursor, sIdx, E);

    gemm1<<<(n + 3) / 4, 256, 0, stream>>>(x, W1, bufA, n);
    gather8<true ><<<(n + 3) / 4, 256, 0, stream>>>(ptr, sIdx, dinv, bufA, b1, bufB, n); // h = relu(Âh1+b1)
    gather8<false><<<(n + 3) / 4, 256, 0, stream>>>(ptr, sIdx, dinv, bufB, b1, bufA, n); // g = Âh
    gemm2_logsm<<<(n + 3) / 4, 256, 0, stream>>>(bufA, W2, b2, out, n);
}

// Round 4
// 523.846 us; speedup vs baseline: 3.1955x; 1.7559x over previous
//
#include <hip/hip_runtime.h>
#include <math.h>

#define F_IN 128
#define HID  64
#define NCLS 40
#define PART_CHUNK 4096

typedef _Float16 half8 __attribute__((ext_vector_type(8)));
typedef float floatx4 __attribute__((ext_vector_type(4)));

// load 8 f16 from an 8B-aligned (not necessarily 16B) pointer
__device__ inline half8 ld_half8_u8(const _Float16* p) {
    union { uint2 u[2]; half8 h; } r;
    r.u[0] = *(const uint2*)p;
    r.u[1] = *(const uint2*)(p + 4);
    return r.h;
}

// ---------------- degree histogram (int) ----------------
__global__ void histo(const int* __restrict__ dst, int E, int* __restrict__ cnt) {
    int e = blockIdx.x * blockDim.x + threadIdx.x;
    if (e < E) atomicAdd(&cnt[dst[e]], 1);
}

__global__ void finalize_dinv(const int* __restrict__ cnt, float* __restrict__ dinv, int n) {
    int i = blockIdx.x * blockDim.x + threadIdx.x;
    if (i < n) dinv[i] = rsqrtf((float)cnt[i] + 1.0f);   // +1 self loop
}

// ---------------- exclusive scan of cnt -> ptr ----------------
__global__ __launch_bounds__(256) void scanA(const int* __restrict__ cnt, int* __restrict__ ptr,
                                             int* __restrict__ bsum, int n) {
    __shared__ int s[256];
    int tid = threadIdx.x;
    int i = blockIdx.x * 256 + tid;
    int v = (i < n) ? cnt[i] : 0;
    s[tid] = v; __syncthreads();
    for (int off = 1; off < 256; off <<= 1) {
        int t = (tid >= off) ? s[tid - off] : 0;
        __syncthreads();
        s[tid] += t;
        __syncthreads();
    }
    if (i < n) ptr[i] = s[tid] - v;
    if (tid == 255) bsum[blockIdx.x] = s[255];
}

__global__ __launch_bounds__(512) void scanB(int* __restrict__ bsum, int nb) {
    __shared__ int s[512];
    int tid = threadIdx.x;
    int v = (tid < nb) ? bsum[tid] : 0;
    s[tid] = v; __syncthreads();
    for (int off = 1; off < 512; off <<= 1) {
        int t = (tid >= off) ? s[tid - off] : 0;
        __syncthreads();
        s[tid] += t;
        __syncthreads();
    }
    if (tid < nb) bsum[tid] = s[tid] - v;
}

// writes final ptr, and initializes per-bucket cursors (bucket = node >> 7)
__global__ __launch_bounds__(256) void scanC(int* __restrict__ ptr, const int* __restrict__ bsum,
                                             int* __restrict__ bCur, int n, int E) {
    int i = blockIdx.x * 256 + threadIdx.x;
    if (i < n) {
        int p = ptr[i] + bsum[blockIdx.x];
        ptr[i] = p;
        if ((i & 127) == 0) bCur[i >> 7] = p;
    }
    if (i == 0) ptr[n] = E;
}

// ---------------- pass 1: partition edges into 128-node dst buckets ----------------
__global__ __launch_bounds__(256) void partition(const int* __restrict__ src,
                                                 const int* __restrict__ dst,
                                                 int* __restrict__ bCur,
                                                 int2* __restrict__ pairBuf, int E, int NB) {
    __shared__ int hcnt[1024];
    __shared__ int hbase[1024];
    int tid = threadIdx.x;
    for (int i = tid; i < NB; i += 256) hcnt[i] = 0;
    __syncthreads();
    int e0 = blockIdx.x * PART_CHUNK;
    int s_[16], d_[16];
#pragma unroll
    for (int i = 0; i < 16; ++i) {
        int e = e0 + i * 256 + tid;
        if (e < E) {
            s_[i] = src[e]; d_[i] = dst[e];
            atomicAdd(&hcnt[d_[i] >> 7], 1);
        }
    }
    __syncthreads();
    for (int b = tid; b < NB; b += 256) {
        int c = hcnt[b];
        hbase[b] = c ? atomicAdd(&bCur[b], c) : 0;
        hcnt[b] = 0;
    }
    __syncthreads();
#pragma unroll
    for (int i = 0; i < 16; ++i) {
        int e = e0 + i * 256 + tid;
        if (e < E) {
            int b = d_[i] >> 7;
            int loc = atomicAdd(&hcnt[b], 1);
            pairBuf[hbase[b] + loc] = make_int2(s_[i], d_[i]);
        }
    }
}

// ---------------- pass 2: within-bucket exact scatter to CSR (L2-local) ----------------
__global__ __launch_bounds__(256) void bucket_scatter(const int* __restrict__ ptr,
                                                      const int2* __restrict__ pairBuf,
                                                      int* __restrict__ sIdx, int n) {
    __shared__ int cur[128];
    int b = blockIdx.x;
    int node0 = b << 7;
    int tid = threadIdx.x;
    if (tid < 128 && node0 + tid < n) cur[tid] = ptr[node0 + tid];
    __syncthreads();
    int beg = ptr[node0];
    int hi = node0 + 128; if (hi > n) hi = n;
    int end = ptr[hi];
    for (int j = beg + tid; j < end; j += 256) {
        int2 p = pairBuf[j];
        int pos = atomicAdd(&cur[p.y & 127], 1);
        sIdx[pos] = p.x;
    }
}

// ---------------- layer 1 GEMM via f16 MFMA: h1 = f16(x @ W1) ----------------
// block = 256 thr (4 waves), 64 nodes x 64 outs, K=128.
#define ASTRIDE 132   // f16 row stride (128 + 4 pad -> 2-way LDS banks, free)
__global__ __launch_bounds__(256) void gemm1_mfma(const float* __restrict__ x,
                                                  const float* __restrict__ W1,
                                                  _Float16* __restrict__ h1, int n) {
    __shared__ _Float16 Ah[64 * ASTRIDE];   // x tile, f16
    __shared__ _Float16 Wt[64 * ASTRIDE];   // W1 transposed: Wt[nout][k]
    int tid = threadIdx.x;
    int node0 = blockIdx.x * 64;
#pragma unroll
    for (int i = 0; i < 8; ++i) {           // stage x: 8192 floats via float4
        int f = (i * 256 + tid) * 4;
        int m = f >> 7, k = f & 127;
        float4 v = (node0 + m < n) ? ((const float4*)(x + (size_t)(node0 + m) * F_IN))[k >> 2]
                                   : make_float4(0.f, 0.f, 0.f, 0.f);
        _Float16* p = &Ah[m * ASTRIDE + k];
        p[0] = (_Float16)v.x; p[1] = (_Float16)v.y; p[2] = (_Float16)v.z; p[3] = (_Float16)v.w;
    }
#pragma unroll
    for (int i = 0; i < 32; ++i) {          // stage W1 transposed
        int f = i * 256 + tid;              // f = k*64 + nout
        int k = f >> 6, nn = f & 63;
        Wt[nn * ASTRIDE + k] = (_Float16)W1[f];
    }
    __syncthreads();
    int wave = tid >> 6, lane = tid & 63;
    int m0 = wave * 16;
    int col = lane & 15, quad = lane >> 4;
    floatx4 acc[4] = {{0,0,0,0},{0,0,0,0},{0,0,0,0},{0,0,0,0}};
#pragma unroll
    for (int kk = 0; kk < 4; ++kk) {
        int kbase = kk * 32 + quad * 8;
        half8 a = ld_half8_u8(&Ah[(m0 + col) * ASTRIDE + kbase]);   // A[m=lane&15][k=quad*8+j]
#pragma unroll
        for (int t = 0; t < 4; ++t) {
            half8 b = ld_half8_u8(&Wt[(t * 16 + col) * ASTRIDE + kbase]); // B[k][n=lane&15]
            acc[t] = __builtin_amdgcn_mfma_f32_16x16x32_f16(a, b, acc[t], 0, 0, 0);
        }
    }
#pragma unroll
    for (int t = 0; t < 4; ++t)
#pragma unroll
        for (int r = 0; r < 4; ++r) {       // C: col=lane&15, row=quad*4+r
            int node = node0 + m0 + quad * 4 + r;
            if (node < n) h1[(size_t)node * HID + t * 16 + col] = (_Float16)acc[t][r];
        }
}

// ---------------- CSR gather on f16 rows: wave/node, 8 lanes/edge, 16 edges/iter ----------------
template<bool RELU>
__global__ __launch_bounds__(256) void gather16(const int* __restrict__ ptr,
                                                const int* __restrict__ sIdx,
                                                const float* __restrict__ dinv,
                                                const _Float16* __restrict__ hin,
                                                const float* __restrict__ bias,
                                                _Float16* __restrict__ hout, int n) {
    int tid = threadIdx.x, lane = tid & 63;
    int node = blockIdx.x * 4 + (tid >> 6);
    if (node >= n) return;
    int grp = lane >> 3;          // edge slot 0..7
    int fq  = lane & 7;           // 8-f16 chunk within 64-f16 row (16B)
    int beg = ptr[node], end = ptr[node + 1];
    float di = dinv[node];
    float a0[8] = {0,0,0,0,0,0,0,0}, a1[8] = {0,0,0,0,0,0,0,0};

    if (grp == 0) {               // self loop
        half8 v = *(const half8*)(hin + (size_t)node * HID + fq * 8);
        float w = di * di;
#pragma unroll
        for (int j = 0; j < 8; ++j) a0[j] = (float)v[j] * w;
    }
    for (int j0 = beg; j0 < end; j0 += 16) {
        int ja = j0 + grp, jb = j0 + 8 + grp;
        bool va = ja < end, vb = jb < end;
        int sa = sIdx[va ? ja : beg];
        int sb = sIdx[vb ? jb : beg];
        float wa = va ? dinv[sa] * di : 0.f;
        float wb = vb ? dinv[sb] * di : 0.f;
        half8 ra = *(const half8*)(hin + (size_t)sa * HID + fq * 8);
        half8 rb = *(const half8*)(hin + (size_t)sb * HID + fq * 8);
#pragma unroll
        for (int j = 0; j < 8; ++j) {
            a0[j] = fmaf((float)ra[j], wa, a0[j]);
            a1[j] = fmaf((float)rb[j], wb, a1[j]);
        }
    }
#pragma unroll
    for (int j = 0; j < 8; ++j) a0[j] += a1[j];
#pragma unroll
    for (int off = 8; off < 64; off <<= 1)
#pragma unroll
        for (int j = 0; j < 8; ++j) a0[j] += __shfl_xor(a0[j], off, 64);
    if (grp == 0) {
        union { half8 h; uint4 u; } o;
#pragma unroll
        for (int j = 0; j < 8; ++j) {
            float v = a0[j];
            if (RELU) v = fmaxf(v + bias[fq * 8 + j], 0.f);
            o.h[j] = (_Float16)v;
        }
        *(uint4*)(hout + (size_t)node * HID + fq * 8) = o.u;
    }
}

// ---------------- out = log_softmax(g @ W2 + b2), wave per node ----------------
__global__ __launch_bounds__(256) void gemm2_logsm(const _Float16* __restrict__ g,
                                                   const float* __restrict__ W2,
                                                   const float* __restrict__ b2,
                                                   float* __restrict__ out, int n) {
    __shared__ float Ws[HID * NCLS];   // 10 KB
    __shared__ float xs[4][HID];
    int tid = threadIdx.x;
    for (int i = tid; i < HID * NCLS; i += 256) Ws[i] = W2[i];
    int node0 = blockIdx.x * 4;
    for (int i = tid; i < 4 * HID; i += 256) {
        int nl = i >> 6, k = i & 63;
        int node = node0 + nl;
        xs[nl][k] = (node < n) ? (float)g[(size_t)node * HID + k] : 0.0f;
    }
    __syncthreads();
    int lane = tid & 63, nl = tid >> 6;
    int node = node0 + nl;
    if (node >= n) return;
    float acc;
    if (lane < NCLS) {
        acc = b2[lane];
#pragma unroll
        for (int k = 0; k < HID; ++k) acc = fmaf(xs[nl][k], Ws[k * NCLS + lane], acc);
    } else {
        acc = -INFINITY;
    }
    float m = acc;
    for (int off = 32; off; off >>= 1) m = fmaxf(m, __shfl_xor(m, off, 64));
    float ex = (lane < NCLS) ? expf(acc - m) : 0.0f;
    float s = ex;
    for (int off = 32; off; off >>= 1) s += __shfl_xor(s, off, 64);
    if (lane < NCLS) out[(size_t)node * NCLS + lane] = acc - m - logf(s);
}

extern "C" void kernel_launch(void* const* d_in, const int* in_sizes, int n_in,
                              void* d_out, int out_size, void* d_ws, size_t ws_size,
                              hipStream_t stream) {
    const float* x  = (const float*)d_in[0];
    const int*   ei = (const int*)d_in[1];
    const float* W1 = (const float*)d_in[2];
    const float* b1 = (const float*)d_in[3];
    const float* W2 = (const float*)d_in[4];
    const float* b2 = (const float*)d_in[5];
    float* out = (float*)d_out;

    int n = in_sizes[0] / F_IN;        // 100000
    int E = in_sizes[1] / 2;           // 3200000
    const int* src = ei;
    const int* dst = ei + E;
    int NB = (n + 127) >> 7;           // 128-node dst buckets (782)

    // workspace layout
    char* ws = (char*)d_ws;
    const size_t MB = 1024 * 1024;
    int*      cnt     = (int*)  (ws);                      // n ints
    int*      ptr     = (int*)  (ws + 1 * 512 * 1024);     // n+1 ints
    int*      bCur    = (int*)  (ws + 2 * 512 * 1024);     // NB ints
    float*    dinv    = (float*)(ws + 3 * 512 * 1024);     // n floats
    int*      bsum    = (int*)  (ws + 4 * 512 * 1024);     // <=512 ints
    int*      sIdx    = (int*)     (ws + 5 * 512 * 1024);            // E ints  (13 MB)
    int2*     pairBuf = (int2*)    (ws + 5 * 512 * 1024 + 13 * MB);  // E int2  (26 MB)
    _Float16* bufA    = (_Float16*)(ws + 5 * 512 * 1024 + 39 * MB);  // n*64 f16 (13 MB): h1, later g
    _Float16* bufB    = (_Float16*)(ws + 5 * 512 * 1024 + 52 * MB);  // n*64 f16 (13 MB): h

    int nbA = (n + 255) / 256;         // scan blocks (<=512)

    hipMemsetAsync(cnt, 0, (size_t)n * sizeof(int), stream);
    histo<<<(E + 255) / 256, 256, 0, stream>>>(dst, E, cnt);
    finalize_dinv<<<nbA, 256, 0, stream>>>(cnt, dinv, n);
    scanA<<<nbA, 256, 0, stream>>>(cnt, ptr, bsum, n);
    scanB<<<1, 512, 0, stream>>>(bsum, nbA);
    scanC<<<nbA, 256, 0, stream>>>(ptr, bsum, bCur, n, E);
    partition<<<(E + PART_CHUNK - 1) / PART_CHUNK, 256, 0, stream>>>(src, dst, bCur, pairBuf, E, NB);
    bucket_scatter<<<NB, 256, 0, stream>>>(ptr, pairBuf, sIdx, n);

    gemm1_mfma<<<(n + 63) / 64, 256, 0, stream>>>(x, W1, bufA, n);
    gather16<true ><<<(n + 3) / 4, 256, 0, stream>>>(ptr, sIdx, dinv, bufA, b1, bufB, n); // h = relu(Âh1+b1)
    gather16<false><<<(n + 3) / 4, 256, 0, stream>>>(ptr, sIdx, dinv, bufB, b1, bufA, n); // g = Âh
    gemm2_logsm<<<(n + 3) / 4, 256, 0, stream>>>(bufA, W2, b2, out, n);
}

// Round 5
// 412.533 us; speedup vs baseline: 4.0577x; 1.2698x over previous
//
#include <hip/hip_runtime.h>
#include <math.h>

#define F_IN 128
#define HID  64
#define NCLS 40
#define PART_CHUNK 4096
#define MAXNB 1024

typedef _Float16 half8 __attribute__((ext_vector_type(8)));
typedef float floatx4 __attribute__((ext_vector_type(4)));

// load 8 f16 from an 8B-aligned (not necessarily 16B) pointer
__device__ inline half8 ld_half8_u8(const _Float16* p) {
    union { uint2 u[2]; half8 h; } r;
    r.u[0] = *(const uint2*)p;
    r.u[1] = *(const uint2*)(p + 4);
    return r.h;
}

// ---------------- bucket-level histogram (LDS-privatized, 782 bins) ----------------
__global__ __launch_bounds__(256) void bucket_histo(const int* __restrict__ dst, int E,
                                                    int* __restrict__ bCnt, int NB) {
    __shared__ int h[MAXNB];
    int tid = threadIdx.x;
    for (int i = tid; i < NB; i += 256) h[i] = 0;
    __syncthreads();
    int e0 = blockIdx.x * PART_CHUNK;
#pragma unroll
    for (int i = 0; i < PART_CHUNK / 256; ++i) {
        int e = e0 + i * 256 + tid;
        if (e < E) atomicAdd(&h[dst[e] >> 7], 1);
    }
    __syncthreads();
    for (int b = tid; b < NB; b += 256) {
        int c = h[b];
        if (c) atomicAdd(&bCnt[b], c);
    }
}

// ---------------- single-block exclusive scan of bucket counts ----------------
__global__ __launch_bounds__(256) void scan_buckets(const int* __restrict__ bCnt,
                                                    int* __restrict__ bBase,
                                                    int* __restrict__ bCur, int NB, int E) {
    __shared__ int part[256];
    int tid = threadIdx.x;
    int v[4]; int sum = 0;
#pragma unroll
    for (int k = 0; k < 4; ++k) {
        int i = tid * 4 + k;
        v[k] = (i < NB) ? bCnt[i] : 0;
        sum += v[k];
    }
    part[tid] = sum; __syncthreads();
    for (int off = 1; off < 256; off <<= 1) {
        int t = (tid >= off) ? part[tid - off] : 0;
        __syncthreads();
        part[tid] += t;
        __syncthreads();
    }
    int base = part[tid] - sum;   // exclusive
#pragma unroll
    for (int k = 0; k < 4; ++k) {
        int i = tid * 4 + k;
        if (i < NB) { bBase[i] = base; bCur[i] = base; }
        base += v[k];
    }
    if (tid == 255) bBase[NB] = E;
}

// ---------------- partition edges into 128-node dst buckets (packed: src<<7 | dst&127) ------
__global__ __launch_bounds__(256) void partition(const int* __restrict__ src,
                                                 const int* __restrict__ dst,
                                                 int* __restrict__ bCur,
                                                 int* __restrict__ pkBuf, int E, int NB) {
    __shared__ int hcnt[MAXNB];
    __shared__ int hbase[MAXNB];
    int tid = threadIdx.x;
    for (int i = tid; i < NB; i += 256) hcnt[i] = 0;
    __syncthreads();
    int e0 = blockIdx.x * PART_CHUNK;
    int s_[16], d_[16];
#pragma unroll
    for (int i = 0; i < 16; ++i) {
        int e = e0 + i * 256 + tid;
        if (e < E) {
            s_[i] = src[e]; d_[i] = dst[e];
            atomicAdd(&hcnt[d_[i] >> 7], 1);
        }
    }
    __syncthreads();
    for (int b = tid; b < NB; b += 256) {
        int c = hcnt[b];
        hbase[b] = c ? atomicAdd(&bCur[b], c) : 0;
        hcnt[b] = 0;
    }
    __syncthreads();
#pragma unroll
    for (int i = 0; i < 16; ++i) {
        int e = e0 + i * 256 + tid;
        if (e < E) {
            int b = d_[i] >> 7;
            int loc = atomicAdd(&hcnt[b], 1);
            pkBuf[hbase[b] + loc] = (s_[i] << 7) | (d_[i] & 127);
        }
    }
}

// ---------------- per-bucket: node counts -> ptr + dinv, then exact scatter to CSR ----------
__global__ __launch_bounds__(256) void bucket_finalize(const int* __restrict__ bBase,
                                                       const int* __restrict__ pkBuf,
                                                       int* __restrict__ ptr,
                                                       float* __restrict__ dinv,
                                                       int* __restrict__ sIdx, int n, int E) {
    __shared__ int cnt128[128];
    __shared__ int sc[128];
    __shared__ int cur[128];
    int b = blockIdx.x;
    int node0 = b << 7;
    int tid = threadIdx.x;
    if (tid < 128) cnt128[tid] = 0;
    __syncthreads();
    int beg = bBase[b], end = bBase[b + 1];
    for (int j = beg + tid; j < end; j += 256)
        atomicAdd(&cnt128[pkBuf[j] & 127], 1);
    __syncthreads();
    int v = (tid < 128) ? cnt128[tid] : 0;
    if (tid < 128) sc[tid] = v;
    __syncthreads();
    for (int off = 1; off < 128; off <<= 1) {
        int t = (tid < 128 && tid >= off) ? sc[tid - off] : 0;
        __syncthreads();
        if (tid < 128) sc[tid] += t;
        __syncthreads();
    }
    if (tid < 128) {
        int node = node0 + tid;
        if (node < n) {
            int p = beg + sc[tid] - v;      // exclusive within bucket + bucket base
            ptr[node] = p;
            cur[tid] = p;
            dinv[node] = rsqrtf((float)v + 1.0f);   // +1 self loop
        }
        if (node == n - 1 || (node == node0 + 127 && node < n)) {
            // last real node of this bucket: nothing extra
        }
    }
    if (tid == 0 && b == gridDim.x - 1) ptr[n] = E;
    __syncthreads();
    for (int j = beg + tid; j < end; j += 256) {
        int p = pkBuf[j];
        int pos = atomicAdd(&cur[p & 127], 1);
        sIdx[pos] = p >> 7;
    }
}

// ---------------- layer 1 GEMM via f16 MFMA: h1 = f16(x @ W1) ----------------
#define ASTRIDE 132   // f16 row stride (128 + 4 pad)
__global__ __launch_bounds__(256) void gemm1_mfma(const float* __restrict__ x,
                                                  const float* __restrict__ W1,
                                                  _Float16* __restrict__ h1, int n) {
    __shared__ _Float16 Ah[64 * ASTRIDE];
    __shared__ _Float16 Wt[64 * ASTRIDE];
    int tid = threadIdx.x;
    int node0 = blockIdx.x * 64;
#pragma unroll
    for (int i = 0; i < 8; ++i) {
        int f = (i * 256 + tid) * 4;
        int m = f >> 7, k = f & 127;
        float4 v = (node0 + m < n) ? ((const float4*)(x + (size_t)(node0 + m) * F_IN))[k >> 2]
                                   : make_float4(0.f, 0.f, 0.f, 0.f);
        _Float16* p = &Ah[m * ASTRIDE + k];
        p[0] = (_Float16)v.x; p[1] = (_Float16)v.y; p[2] = (_Float16)v.z; p[3] = (_Float16)v.w;
    }
#pragma unroll
    for (int i = 0; i < 32; ++i) {
        int f = i * 256 + tid;              // f = k*64 + nout
        int k = f >> 6, nn = f & 63;
        Wt[nn * ASTRIDE + k] = (_Float16)W1[f];
    }
    __syncthreads();
    int wave = tid >> 6, lane = tid & 63;
    int m0 = wave * 16;
    int col = lane & 15, quad = lane >> 4;
    floatx4 acc[4] = {{0,0,0,0},{0,0,0,0},{0,0,0,0},{0,0,0,0}};
#pragma unroll
    for (int kk = 0; kk < 4; ++kk) {
        int kbase = kk * 32 + quad * 8;
        half8 a = ld_half8_u8(&Ah[(m0 + col) * ASTRIDE + kbase]);
#pragma unroll
        for (int t = 0; t < 4; ++t) {
            half8 b = ld_half8_u8(&Wt[(t * 16 + col) * ASTRIDE + kbase]);
            acc[t] = __builtin_amdgcn_mfma_f32_16x16x32_f16(a, b, acc[t], 0, 0, 0);
        }
    }
#pragma unroll
    for (int t = 0; t < 4; ++t)
#pragma unroll
        for (int r = 0; r < 4; ++r) {
            int node = node0 + m0 + quad * 4 + r;
            if (node < n) h1[(size_t)node * HID + t * 16 + col] = (_Float16)acc[t][r];
        }
}

// ---------------- CSR gather on f16 rows: wave/node, 8 lanes/edge, 16 edges/iter ----------
template<bool RELU>
__global__ __launch_bounds__(256) void gather16(const int* __restrict__ ptr,
                                                const int* __restrict__ sIdx,
                                                const float* __restrict__ dinv,
                                                const _Float16* __restrict__ hin,
                                                const float* __restrict__ bias,
                                                _Float16* __restrict__ hout, int n) {
    int tid = threadIdx.x, lane = tid & 63;
    int node = blockIdx.x * 4 + (tid >> 6);
    if (node >= n) return;
    int grp = lane >> 3;          // edge slot 0..7
    int fq  = lane & 7;           // 16B chunk within 128B row
    int beg = ptr[node], end = ptr[node + 1];
    float di = dinv[node];
    float a0[8] = {0,0,0,0,0,0,0,0}, a1[8] = {0,0,0,0,0,0,0,0};

    if (grp == 0) {               // self loop
        half8 v = *(const half8*)(hin + (size_t)node * HID + fq * 8);
        float w = di * di;
#pragma unroll
        for (int j = 0; j < 8; ++j) a0[j] = (float)v[j] * w;
    }
    for (int j0 = beg; j0 < end; j0 += 16) {
        int ja = j0 + grp, jb = j0 + 8 + grp;
        bool va = ja < end, vb = jb < end;
        int sa = sIdx[va ? ja : beg];
        int sb = sIdx[vb ? jb : beg];
        float wa = va ? dinv[sa] * di : 0.f;
        float wb = vb ? dinv[sb] * di : 0.f;
        half8 ra = *(const half8*)(hin + (size_t)sa * HID + fq * 8);
        half8 rb = *(const half8*)(hin + (size_t)sb * HID + fq * 8);
#pragma unroll
        for (int j = 0; j < 8; ++j) {
            a0[j] = fmaf((float)ra[j], wa, a0[j]);
            a1[j] = fmaf((float)rb[j], wb, a1[j]);
        }
    }
#pragma unroll
    for (int j = 0; j < 8; ++j) a0[j] += a1[j];
#pragma unroll
    for (int off = 8; off < 64; off <<= 1)
#pragma unroll
        for (int j = 0; j < 8; ++j) a0[j] += __shfl_xor(a0[j], off, 64);
    if (grp == 0) {
        union { half8 h; uint4 u; } o;
#pragma unroll
        for (int j = 0; j < 8; ++j) {
            float v = a0[j];
            if (RELU) v = fmaxf(v + bias[fq * 8 + j], 0.f);
            o.h[j] = (_Float16)v;
        }
        *(uint4*)(hout + (size_t)node * HID + fq * 8) = o.u;
    }
}

// ---------------- out = log_softmax(g @ W2 + b2), wave per node ----------------
__global__ __launch_bounds__(256) void gemm2_logsm(const _Float16* __restrict__ g,
                                                   const float* __restrict__ W2,
                                                   const float* __restrict__ b2,
                                                   float* __restrict__ out, int n) {
    __shared__ float Ws[HID * NCLS];
    __shared__ float xs[4][HID];
    int tid = threadIdx.x;
    for (int i = tid; i < HID * NCLS; i += 256) Ws[i] = W2[i];
    int node0 = blockIdx.x * 4;
    for (int i = tid; i < 4 * HID; i += 256) {
        int nl = i >> 6, k = i & 63;
        int node = node0 + nl;
        xs[nl][k] = (node < n) ? (float)g[(size_t)node * HID + k] : 0.0f;
    }
    __syncthreads();
    int lane = tid & 63, nl = tid >> 6;
    int node = node0 + nl;
    if (node >= n) return;
    float acc;
    if (lane < NCLS) {
        acc = b2[lane];
#pragma unroll
        for (int k = 0; k < HID; ++k) acc = fmaf(xs[nl][k], Ws[k * NCLS + lane], acc);
    } else {
        acc = -INFINITY;
    }
    float m = acc;
    for (int off = 32; off; off >>= 1) m = fmaxf(m, __shfl_xor(m, off, 64));
    float ex = (lane < NCLS) ? expf(acc - m) : 0.0f;
    float s = ex;
    for (int off = 32; off; off >>= 1) s += __shfl_xor(s, off, 64);
    if (lane < NCLS) out[(size_t)node * NCLS + lane] = acc - m - logf(s);
}

extern "C" void kernel_launch(void* const* d_in, const int* in_sizes, int n_in,
                              void* d_out, int out_size, void* d_ws, size_t ws_size,
                              hipStream_t stream) {
    const float* x  = (const float*)d_in[0];
    const int*   ei = (const int*)d_in[1];
    const float* W1 = (const float*)d_in[2];
    const float* b1 = (const float*)d_in[3];
    const float* W2 = (const float*)d_in[4];
    const float* b2 = (const float*)d_in[5];
    float* out = (float*)d_out;

    int n = in_sizes[0] / F_IN;        // 100000
    int E = in_sizes[1] / 2;           // 3200000
    const int* src = ei;
    const int* dst = ei + E;
    int NB = (n + 127) >> 7;           // 782 dst buckets
    int NCH = (E + PART_CHUNK - 1) / PART_CHUNK;

    // workspace layout
    char* ws = (char*)d_ws;
    const size_t MB = 1024 * 1024;
    int*      bCnt  = (int*)  (ws);                      // NB ints
    int*      bBase = (int*)  (ws + 64 * 1024);          // NB+1 ints
    int*      bCur  = (int*)  (ws + 128 * 1024);         // NB ints
    int*      ptr   = (int*)  (ws + 192 * 1024);         // n+1 ints (0.4 MB)
    float*    dinv  = (float*)(ws + 1 * MB);             // n floats
    int*      sIdx  = (int*)     (ws + 2 * MB);          // E ints  (13 MB)
    int*      pkBuf = (int*)     (ws + 15 * MB);         // E ints  (13 MB)
    _Float16* bufA  = (_Float16*)(ws + 28 * MB);         // n*64 f16 (12.8 MB): h1, later g
    _Float16* bufB  = (_Float16*)(ws + 41 * MB);         // n*64 f16 (12.8 MB): h

    hipMemsetAsync(bCnt, 0, (size_t)NB * sizeof(int), stream);
    bucket_histo<<<NCH, 256, 0, stream>>>(dst, E, bCnt, NB);
    scan_buckets<<<1, 256, 0, stream>>>(bCnt, bBase, bCur, NB, E);
    partition<<<NCH, 256, 0, stream>>>(src, dst, bCur, pkBuf, E, NB);
    bucket_finalize<<<NB, 256, 0, stream>>>(bBase, pkBuf, ptr, dinv, sIdx, n, E);

    gemm1_mfma<<<(n + 63) / 64, 256, 0, stream>>>(x, W1, bufA, n);
    gather16<true ><<<(n + 3) / 4, 256, 0, stream>>>(ptr, sIdx, dinv, bufA, b1, bufB, n); // h
    gather16<false><<<(n + 3) / 4, 256, 0, stream>>>(ptr, sIdx, dinv, bufB, b1, bufA, n); // g
    gemm2_logsm<<<(n + 3) / 4, 256, 0, stream>>>(bufA, W2, b2, out, n);
}